// Round 19
// baseline (493.389 us; speedup 1.0000x reference)
//
#include <hip/hip_runtime.h>
#include <hip/hip_bf16.h>
#include <cstdint>

#define B_IMG 512
#define NMEM  32768
#define DD    4096
#define HID   16

typedef __attribute__((ext_vector_type(8))) short short8;
typedef __attribute__((ext_vector_type(4))) float f32x4;
typedef unsigned long long ull;

__device__ __forceinline__ void gload16(const void* g, const void* l) {
  __builtin_amdgcn_global_load_lds(
      (const __attribute__((address_space(1))) void*)g,
      (__attribute__((address_space(3))) void*)l, 16, 0, 0);
}

__device__ __forceinline__ ushort to_bf16u(float f) {
  uint32_t u = __float_as_uint(f);
  return (ushort)((u + 0x7fffu + ((u >> 16) & 1u)) >> 16);
}

__device__ __forceinline__ uint32_t cvtpk(float lo, float hi) {
  uint32_t r;
  asm("v_cvt_pk_bf16_f32 %0, %1, %2" : "=v"(r) : "v"(lo), "v"(hi));
  return r;
}

// ---------------- squared row norms (fallback path) ----------------
__global__ __launch_bounds__(256) void sqnorm_kernel(const float* __restrict__ x,
                                                     float* __restrict__ out) {
  const int row = blockIdx.x;
  const float4* p = reinterpret_cast<const float4*>(x + (size_t)row * DD);
  float s = 0.f;
#pragma unroll
  for (int j = 0; j < 4; ++j) {
    float4 v = p[threadIdx.x + 256 * j];
    s += v.x * v.x + v.y * v.y + v.z * v.z + v.w * v.w;
  }
#pragma unroll
  for (int o = 32; o > 0; o >>= 1) s += __shfl_down(s, o);
  __shared__ float ls[4];
  if ((threadIdx.x & 63) == 0) ls[threadIdx.x >> 6] = s;
  __syncthreads();
  if (threadIdx.x == 0) out[row] = (ls[0] + ls[1]) + (ls[2] + ls[3]);
}

// ---------------- split f32 -> bf16 hi + row sqnorm (A side only) ----------------
__global__ __launch_bounds__(256) void split_hi_kernel(const float* __restrict__ x,
                                                       ushort* __restrict__ hi,
                                                       float* __restrict__ nrm) {
  const int row = blockIdx.x;
  const int t = threadIdx.x;
  const float4* p = reinterpret_cast<const float4*>(x + (size_t)row * DD);
  ushort4* ph = reinterpret_cast<ushort4*>(hi + (size_t)row * DD);
  float s = 0.f;
#pragma unroll
  for (int j = 0; j < 4; ++j) {
    float4 v = p[t + 256 * j];
    float vv[4] = {v.x, v.y, v.z, v.w};
    ushort4 h;
    ushort* hp = &h.x;
#pragma unroll
    for (int q = 0; q < 4; ++q) {
      float f = vv[q];
      s += f * f;
      hp[q] = to_bf16u(f);
    }
    ph[t + 256 * j] = h;
  }
#pragma unroll
  for (int o = 32; o > 0; o >>= 1) s += __shfl_down(s, o);
  __shared__ float ls[4];
  if ((t & 63) == 0) ls[t >> 6] = s;
  __syncthreads();
  if (t == 0) nrm[row] = (ls[0] + ls[1]) + (ls[2] + ls[3]);
}

// ---------------- pass 1: bf16 MFMA dist GEMM, B converted inline, BK=64 ------------
// r12 schedule widened to a 128m x 256n tile (8 waves, 2m x 4n): 32 MFMA per wave per
// barrier pair -> barrier-drain events per FLOP halved again (r12's proven lever).
__global__ __launch_bounds__(512) void dist1f_kernel(
    const ushort* __restrict__ Ah_g, const float* __restrict__ Bf,
    const float* __restrict__ a2, float* __restrict__ dists) {
  const int d = blockIdx.x;
  const int xcd = d & 7;
  const int rest = d >> 3;           // 0..63
  const int mb = rest & 3;
  const int nb = (rest >> 2) * 8 + xcd;   // 0..127
  const int m0 = mb * 128;
  const int n0 = nb * 256;

  __shared__ __align__(16) char la[16384];   // Ah tile 128x64 bf16 (two 128x32 halves)
  __shared__ __align__(16) char lbB[32768];  // B tile 256x64 bf16 (two 256x32 halves)
  __shared__ float b2loc[256];

  const int t = threadIdx.x;
  const int lane = t & 63;
  const int wid = t >> 6;        // 0..7
  const int wm = wid >> 2;       // 0..1 -> 64-row band
  const int wn = wid & 3;        // 0..3 -> 64-col band

  f32x4 acc[4][4];
#pragma unroll
  for (int mi = 0; mi < 4; ++mi)
#pragma unroll
    for (int ni = 0; ni < 4; ++ni) {
      f32x4 z = {0.f, 0.f, 0.f, 0.f};
      acc[mi][ni] = z;
    }

  // B staging: thread t owns local rows r0=t>>2 and r1=128+r0, granule g0=t&3;
  // swizzled col identical for both ( ((r+128)>>1)&3 == (r>>1)&3 ).
  const int r0 = t >> 2, g0 = t & 3;
  const int c0 = ((g0 ^ ((r0 >> 1) & 3)) << 3);
  const int r1 = 128 + r0;
  const float* Bp0 = Bf + (size_t)(n0 + r0) * DD + c0;
  const float* Bp1 = Bf + (size_t)(n0 + r1) * DD + c0;
  float s0 = 0.f, s1 = 0.f;

  // A staging: thread t owns granule t of each 8192B half
  const int arow = t >> 2;
  const int acol = ((g0 ^ ((arow >> 1) & 3)) << 3);

  for (int k0 = 0; k0 < DD; k0 += 64) {
    // A: async global->LDS first (older in vmcnt FIFO -> hidden under B flat wait)
#pragma unroll
    for (int h = 0; h < 2; ++h)
      gload16(Ah_g + ((size_t)(m0 + arow) * DD + k0 + h * 32 + acol),
              la + h * 8192 + t * 16);
    // B: reg-stage f32, accumulate norms, convert, write LDS (both halves, both rows)
#pragma unroll
    for (int h = 0; h < 2; ++h) {
      float4 f00 = *(const float4*)(Bp0 + k0 + h * 32);
      float4 f01 = *(const float4*)(Bp0 + k0 + h * 32 + 4);
      float4 f10 = *(const float4*)(Bp1 + k0 + h * 32);
      float4 f11 = *(const float4*)(Bp1 + k0 + h * 32 + 4);
      s0 += f00.x * f00.x + f00.y * f00.y + f00.z * f00.z + f00.w * f00.w;
      s0 += f01.x * f01.x + f01.y * f01.y + f01.z * f01.z + f01.w * f01.w;
      s1 += f10.x * f10.x + f10.y * f10.y + f10.z * f10.z + f10.w * f10.w;
      s1 += f11.x * f11.x + f11.y * f11.y + f11.z * f11.z + f11.w * f11.w;
      uint4 p0, p1;
      p0.x = cvtpk(f00.x, f00.y); p0.y = cvtpk(f00.z, f00.w);
      p0.z = cvtpk(f01.x, f01.y); p0.w = cvtpk(f01.z, f01.w);
      p1.x = cvtpk(f10.x, f10.y); p1.y = cvtpk(f10.z, f10.w);
      p1.z = cvtpk(f11.x, f11.y); p1.w = cvtpk(f11.z, f11.w);
      *(uint4*)(lbB + h * 16384 + t * 16) = p0;           // local row r0
      *(uint4*)(lbB + h * 16384 + 8192 + t * 16) = p1;    // local row 128+r0
    }
    __syncthreads();  // drains A gloads (done during B wait) + ds_writes

    // ---- 32 MFMAs per wave over the two 32-col halves ----
#pragma unroll
    for (int h = 0; h < 2; ++h) {
      short8 ah[4];
#pragma unroll
      for (int mi = 0; mi < 4; ++mi) {
        const int r = wm * 64 + mi * 16 + (lane & 15);
        const int off = r * 64 + ((((lane >> 4) ^ (r >> 1)) & 3) << 4);
        ah[mi] = *(const short8*)(la + h * 8192 + off);
      }
#pragma unroll
      for (int ni = 0; ni < 4; ++ni) {
        const int r = wn * 64 + ni * 16 + (lane & 15);
        const int off = r * 64 + ((((lane >> 4) ^ (r >> 1)) & 3) << 4);
        short8 bh = *(const short8*)(lbB + h * 16384 + off);
#pragma unroll
        for (int mi = 0; mi < 4; ++mi)
          acc[mi][ni] = __builtin_amdgcn_mfma_f32_16x16x32_bf16(ah[mi], bh, acc[mi][ni], 0, 0, 0);
      }
    }
    __syncthreads();
  }

  // finalize per-row b2 (4-lane quad reduce; quads never cross a wave)
  s0 += __shfl_xor(s0, 1); s0 += __shfl_xor(s0, 2);
  s1 += __shfl_xor(s1, 1); s1 += __shfl_xor(s1, 2);
  if ((t & 3) == 0) { b2loc[r0] = s0; b2loc[r1] = s1; }
  __syncthreads();

  // epilogue: approx dist -> global
#pragma unroll
  for (int mi = 0; mi < 4; ++mi)
#pragma unroll
    for (int j = 0; j < 4; ++j) {
      const int m = m0 + wm * 64 + mi * 16 + (lane >> 4) * 4 + j;
      const float a2v = a2[m];
#pragma unroll
      for (int ni = 0; ni < 4; ++ni) {
        const int nl = wn * 64 + ni * 16 + (lane & 15);
        dists[(size_t)m * NMEM + n0 + nl] = (a2v + b2loc[nl]) - 2.0f * acc[mi][ni][j];
      }
    }
}

// ---------------- pass 2: chunked approx-min -> candidates -> exact refine ----------------
#define MARGIN 4.0f
#define MAXC 64
#define NCH 4
#define CHW (NMEM / NCH)
__global__ __launch_bounds__(256) void refine_kernel(
    const float* __restrict__ dists, const float* __restrict__ A,
    const float* __restrict__ Bm, const float* __restrict__ a2,
    ull* __restrict__ best) {
  const int m = blockIdx.x;
  const int base = blockIdx.y * CHW;
  const int t = threadIdx.x;
  const int lane = t & 63, wid = t >> 6;
  const float4* r4 = reinterpret_cast<const float4*>(dists + (size_t)m * NMEM + base);

  float lmin = 3.4e38f;
  for (int i = t; i < CHW / 4; i += 256) {
    float4 v = r4[i];
    lmin = fminf(lmin, fminf(fminf(v.x, v.y), fminf(v.z, v.w)));
  }
#pragma unroll
  for (int o = 32; o > 0; o >>= 1) lmin = fminf(lmin, __shfl_down(lmin, o));
  __shared__ float ws4[4];
  __shared__ float red[4];
  __shared__ float red2[4];
  __shared__ int cnt;
  __shared__ int cand[MAXC];
  if (lane == 0) ws4[wid] = lmin;
  if (t == 0) cnt = 0;
  __syncthreads();
  const float thresh = fminf(fminf(ws4[0], ws4[1]), fminf(ws4[2], ws4[3])) + MARGIN;

  for (int i = t; i < CHW / 4; i += 256) {
    float4 v = r4[i];
    float vv[4] = {v.x, v.y, v.z, v.w};
#pragma unroll
    for (int q = 0; q < 4; ++q)
      if (vv[q] < thresh) {
        int c = atomicAdd(&cnt, 1);
        if (c < MAXC) cand[c] = base + i * 4 + q;
      }
  }
  __syncthreads();
  const int nc = min(cnt, MAXC);

  ull bkey = ~0ull;
  const float4* a4 = reinterpret_cast<const float4*>(A + (size_t)m * DD);
  for (int c = 0; c < nc; ++c) {
    const int n = cand[c];
    const float4* b4 = reinterpret_cast<const float4*>(Bm + (size_t)n * DD);
    float s = 0.f, s2 = 0.f;
    for (int i = t; i < DD / 4; i += 256) {
      float4 av = a4[i], bv = b4[i];
      s += av.x * bv.x + av.y * bv.y + av.z * bv.z + av.w * bv.w;
      s2 += bv.x * bv.x + bv.y * bv.y + bv.z * bv.z + bv.w * bv.w;
    }
#pragma unroll
    for (int o = 32; o > 0; o >>= 1) {
      s += __shfl_down(s, o);
      s2 += __shfl_down(s2, o);
    }
    if (lane == 0) { red[wid] = s; red2[wid] = s2; }
    __syncthreads();
    if (t == 0) {
      const float dot = (red[0] + red[1]) + (red[2] + red[3]);
      const float b2n = (red2[0] + red2[1]) + (red2[2] + red2[3]);
      const float dv = (a2[m] + b2n) - 2.0f * dot;
      const ull key = ((ull)__float_as_uint(dv) << 32) | (unsigned)n;
      if (key < bkey) bkey = key;
    }
    __syncthreads();
  }
  if (t == 0) atomicMin(&best[m], bkey);
}

// ---------------- fp32 fallback distance GEMM + argmin ----------------
__global__ __launch_bounds__(256) void dist_argmin_kernel(
    const float* __restrict__ A, const float* __restrict__ Bm,
    const float* __restrict__ a2, const float* __restrict__ b2,
    ull* __restrict__ best) {
  __shared__ float As[32][128];
  __shared__ float Bs[32][128];
  const int tid = threadIdx.x;
  const int m0 = blockIdx.y * 128;
  const int n0 = blockIdx.x * 128;
  const int tm = tid >> 4, tn = tid & 15;
  const int sr = tid >> 3;
  const int sc = (tid & 7) << 2;
  float acc[8][8];
#pragma unroll
  for (int i = 0; i < 8; ++i)
#pragma unroll
    for (int j = 0; j < 8; ++j) acc[i][j] = 0.f;
  for (int k0 = 0; k0 < DD; k0 += 32) {
    __syncthreads();
#pragma unroll
    for (int r = 0; r < 4; ++r) {
      const int row = sr + (r << 5);
      float4 va = *reinterpret_cast<const float4*>(&A[(size_t)(m0 + row) * DD + k0 + sc]);
      As[sc + 0][row] = va.x; As[sc + 1][row] = va.y;
      As[sc + 2][row] = va.z; As[sc + 3][row] = va.w;
      float4 vb = *reinterpret_cast<const float4*>(&Bm[(size_t)(n0 + row) * DD + k0 + sc]);
      Bs[sc + 0][row] = vb.x; Bs[sc + 1][row] = vb.y;
      Bs[sc + 2][row] = vb.z; Bs[sc + 3][row] = vb.w;
    }
    __syncthreads();
#pragma unroll 8
    for (int kk = 0; kk < 32; ++kk) {
      float4 a0 = *reinterpret_cast<const float4*>(&As[kk][tm * 8]);
      float4 a1 = *reinterpret_cast<const float4*>(&As[kk][tm * 8 + 4]);
      float4 b0 = *reinterpret_cast<const float4*>(&Bs[kk][tn * 8]);
      float4 b1 = *reinterpret_cast<const float4*>(&Bs[kk][tn * 8 + 4]);
      float a[8] = {a0.x, a0.y, a0.z, a0.w, a1.x, a1.y, a1.z, a1.w};
      float b[8] = {b0.x, b0.y, b0.z, b0.w, b1.x, b1.y, b1.z, b1.w};
#pragma unroll
      for (int i = 0; i < 8; ++i)
#pragma unroll
        for (int j = 0; j < 8; ++j) acc[i][j] += a[i] * b[j];
    }
  }
  __syncthreads();
  ull* red = reinterpret_cast<ull*>(&As[0][0]);
#pragma unroll
  for (int i = 0; i < 8; ++i) {
    const int m = m0 + tm * 8 + i;
    const float a2v = a2[m];
    float bd = 3.4e38f;
    int bn = 0;
#pragma unroll
    for (int j = 0; j < 8; ++j) {
      const int n = n0 + tn * 8 + j;
      const float dval = (a2v + b2[n]) - 2.0f * acc[i][j];
      if (dval < bd) { bd = dval; bn = n; }
    }
    red[(tm * 8 + i) * 16 + tn] = ((ull)__float_as_uint(bd) << 32) | (unsigned)bn;
  }
  __syncthreads();
  if (tid < 128) {
    ull k = red[tid * 16];
#pragma unroll
    for (int t2 = 1; t2 < 16; ++t2) {
      ull c = red[tid * 16 + t2];
      if (c < k) k = c;
    }
    atomicMin(&best[m0 + tid], k);
  }
}

// ---------------- weight prep per pipeline ----------------
// wh1/wl1: [co][32k] bf16 hi/lo, k = ci*9+tap (k >= ncin*9 -> 0)  (L1 MFMA A-operand)
// wh2/wl2: [co][160] bf16 hi/lo, k = tap*16+ci
// wh3/wl3: [16][160] bf16 hi/lo, row 0 = w3
__global__ __launch_bounds__(256) void wprep_kernel(
    const float* __restrict__ w1, const float* __restrict__ w2,
    const float* __restrict__ w3, int ncin,
    ushort* __restrict__ wh1, ushort* __restrict__ wl1,
    ushort* __restrict__ wh2, ushort* __restrict__ wl2,
    ushort* __restrict__ wh3, ushort* __restrict__ wl3) {
  const int i = blockIdx.x * 256 + threadIdx.x;
  if (i < 512) {
    const int co = i >> 5, k = i & 31;
    float f = 0.f;
    if (k < ncin * 9) f = w1[(co * ncin + k / 9) * 9 + (k % 9)];
    const ushort hb = to_bf16u(f);
    const float fl = f - __uint_as_float((uint32_t)hb << 16);
    wh1[i] = hb;
    wl1[i] = to_bf16u(fl);
  } else if (i < 512 + 5120) {
    const int j = i - 512;
    const int which = j / 2560;        // 0 -> L2, 1 -> L3
    const int jj = j % 2560;
    const int co = jj / 160, k = jj % 160;
    float f = 0.f;
    if (which == 0) {
      if (k < 144) f = w2[co * 144 + (k & 15) * 9 + (k >> 4)];
    } else {
      if (co == 0 && k < 144) f = w3[(k & 15) * 9 + (k >> 4)];
    }
    const ushort hb = to_bf16u(f);
    const float fl = f - __uint_as_float((uint32_t)hb << 16);
    ushort* dh = (which == 0) ? wh2 : wh3;
    ushort* dl = (which == 0) ? wl2 : wl3;
    dh[co * 160 + k] = hb;
    dl[co * 160 + k] = to_bf16u(fl);
  }
}

// ---------------- fused 3-layer conv: ALL layers MFMA ----------------
template <int NCIN>
__global__ __launch_bounds__(256, 4) void fused_conv3_kernel(
    const float* __restrict__ chan0, const float* __restrict__ chan1,
    const float* __restrict__ memC, const ull* __restrict__ best,
    const ushort* __restrict__ wh1, const ushort* __restrict__ wl1,
    const float* __restrict__ b1v,
    const ushort* __restrict__ wh2, const ushort* __restrict__ wl2,
    const float* __restrict__ b2v,
    const ushort* __restrict__ wh3, const ushort* __restrict__ wl3,
    const float* __restrict__ b3v,
    const float* __restrict__ addend, float sign, float* __restrict__ outp) {
  constexpr int SIN_SZ = NCIN * 1600;      // [ci][20][20] f32
  constexpr int H1 = SIN_SZ;               // 2 planes x 5184 B
  constexpr int H2 = H1 + 10368;           // 2 planes x 5184 B
  constexpr int ZP = H2 + 10368;           // 64 B zeros
  constexpr int SB = ZP + 64;              // 16 f32 b1 | 16 f32 b2
  __shared__ __align__(16) char smem[SB + 128];
  float* sIn = (float*)smem;
  float* sB = (float*)(smem + SB);

  const int tid = threadIdx.x;
  const int lane = tid & 63, wid = tid >> 6;
  const int img = blockIdx.x / 25;
  const int t = blockIdx.x % 25;
  const int y0 = (t / 5) * 14, x0 = (t % 5) * 14;

  const float* cptr[NCIN];
  cptr[0] = chan0 + (size_t)img * DD;
  if (NCIN == 3) {
    cptr[1] = chan1 + (size_t)img * DD;
    cptr[2] = memC + (size_t)(unsigned)(best[img] & 0xffffffffull) * DD;
  }

  if (tid < 16) *(float*)(smem + ZP + tid * 4) = 0.f;
  if (tid < 16) sB[tid] = b1v[tid];
  else if (tid < 32) sB[tid] = b2v[tid - 16];
  // stage input 20x20 per channel (global offset -3)
  for (int i = tid; i < NCIN * 400; i += 256) {
    const int ci = i / 400, r = i % 400, yy = r / 20, xx = r % 20;
    const int gy = y0 + yy - 3, gx = x0 + xx - 3;
    float v = 0.f;
    if (gy >= 0 && gy < 64 && gx >= 0 && gx < 64) v = cptr[ci][gy * 64 + gx];
    sIn[ci * 400 + yy * 20 + xx] = v;
  }
  __syncthreads();

  // ---- L1 (MFMA): D[co][px] over 18x18 px, K = ci*9+tap padded to 32 ----
  {
    const int xn15 = lane & 15;
    const int kb = (lane >> 4) * 8;
    const short8 a_hi = *(const short8*)(wh1 + xn15 * 32 + kb);
    const short8 a_lo = *(const short8*)(wl1 + xn15 * 32 + kb);
    int koff[8];
    bool kval[8];
#pragma unroll
    for (int e = 0; e < 8; ++e) {
      const int k = kb + e;
      kval[e] = (k < NCIN * 9);
      const int ci = k / 9, kk = k % 9;
      koff[e] = ci * 400 + (kk / 3) * 20 + (kk % 3);
    }
    for (int g = wid; g < 21; g += 4) {
      const int pxl = g * 16 + xn15;
      const bool pv = (pxl < 324);
      const int py = pxl / 18, pxx = pxl % 18;
      const int pbase = py * 20 + pxx;
      float v[8];
#pragma unroll
      for (int e = 0; e < 8; ++e)
        v[e] = (kval[e] && pv) ? sIn[pbase + koff[e]] : 0.f;
      uint4 bu;
      bu.x = cvtpk(v[0], v[1]); bu.y = cvtpk(v[2], v[3]);
      bu.z = cvtpk(v[4], v[5]); bu.w = cvtpk(v[6], v[7]);
      short8 b = *reinterpret_cast<short8*>(&bu);
      f32x4 z = {0.f, 0.f, 0.f, 0.f};
      f32x4 a1 = __builtin_amdgcn_mfma_f32_16x16x32_bf16(a_lo, b, z, 0, 0, 0);
      a1 = __builtin_amdgcn_mfma_f32_16x16x32_bf16(a_hi, b, a1, 0, 0, 0);
      const int gy = y0 + py - 2, gx = x0 + pxx - 2;
      const bool inimg = pv && ((unsigned)gy < 64u) && ((unsigned)gx < 64u);
      if (pv) {
#pragma unroll
        for (int j = 0; j < 4; ++j) {
          const int co = (lane >> 4) * 4 + j;
          const float val = inimg ? fmaxf(a1[j] + sB[co], 0.f) : 0.f;
          *(ushort*)(smem + H1 + (co >> 3) * 5184 + pxl * 16 + (co & 7) * 2) =
              to_bf16u(val);
        }
      }
    }
  }
  __syncthreads();

  // ---- L2 (MFMA) -> h2 bf16 planes on 16x16 grid; zero outside image ----
  const int xn = lane & 15;
  const int xk = lane >> 4;
  f32x4 acc2[4];
#pragma unroll
  for (int g = 0; g < 4; ++g) { f32x4 z = {0.f, 0.f, 0.f, 0.f}; acc2[g] = z; }
#pragma unroll
  for (int kq = 0; kq < 5; ++kq) {
    const int k0 = kq * 32;
    const int we = xn * 160 + k0 + xk * 8;
    short8 ah = *(const short8*)(wh2 + we);
    short8 al = *(const short8*)(wl2 + we);
    const int kb = k0 + xk * 8;
    const int tap = kb >> 4, cih = (kb >> 3) & 1;
    const bool zp = (tap >= 9);
    const int dy = tap / 3, dx = tap % 3;
    const int bbase = H1 + cih * 5184 + ((dy * 18) + xn + dx) * 16;
#pragma unroll
    for (int g = 0; g < 4; ++g) {
      const int y = wid * 4 + g;
      const int boff = zp ? ZP : (bbase + y * 288);
      short8 b = *(const short8*)(smem + boff);
      acc2[g] = __builtin_amdgcn_mfma_f32_16x16x32_bf16(ah, b, acc2[g], 0, 0, 0);
      acc2[g] = __builtin_amdgcn_mfma_f32_16x16x32_bf16(al, b, acc2[g], 0, 0, 0);
    }
  }
#pragma unroll
  for (int g = 0; g < 4; ++g) {
    const int y = wid * 4 + g;
    const int gy = y0 + y - 1, gx = x0 + xn - 1;
    const bool inimg = ((unsigned)gy < 64u) && ((unsigned)gx < 64u);
#pragma unroll
    for (int j = 0; j < 4; ++j) {
      const int co = xk * 4 + j;
      const float v = inimg ? fmaxf(acc2[g][j] + sB[16 + co], 0.f) : 0.f;
      *(ushort*)(smem + H2 + (co >> 3) * 5184 + (y * 18 + xn) * 16 + (co & 7) * 2) =
          to_bf16u(v);
    }
  }
  __syncthreads();

  // ---- L3 (MFMA, only D-row co=0 used) + epilogue on 14x14 ----
  f32x4 acc3[4];
#pragma unroll
  for (int g = 0; g < 4; ++g) { f32x4 z = {0.f, 0.f, 0.f, 0.f}; acc3[g] = z; }
#pragma unroll
  for (int kq = 0; kq < 5; ++kq) {
    const int k0 = kq * 32;
    const int we = xn * 160 + k0 + xk * 8;
    short8 ah = *(const short8*)(wh3 + we);
    short8 al = *(const short8*)(wl3 + we);
    const int kb = k0 + xk * 8;
    const int tap = kb >> 4, cih = (kb >> 3) & 1;
    const bool zp = (tap >= 9);
    const int dy = tap / 3, dx = tap % 3;
    const int bbase = H2 + cih * 5184 + ((dy * 18) + xn + dx) * 16;
#pragma unroll
    for (int g = 0; g < 4; ++g) {
      const int y = wid * 4 + g;
      const int boff = zp ? ZP : (bbase + y * 288);
      short8 b = *(const short8*)(smem + boff);
      acc3[g] = __builtin_amdgcn_mfma_f32_16x16x32_bf16(ah, b, acc3[g], 0, 0, 0);
      acc3[g] = __builtin_amdgcn_mfma_f32_16x16x32_bf16(al, b, acc3[g], 0, 0, 0);
    }
  }
  if (xk == 0) {
#pragma unroll
    for (int g = 0; g < 4; ++g) {
      const int y = wid * 4 + g;
      const int gy = y0 + y, gx = x0 + xn;
      if (y < 14 && xn < 14 && gy < 64 && gx < 64) {
        const size_t o = (size_t)img * DD + gy * 64 + gx;
        outp[o] = addend[o] + sign * (acc3[g][0] + b3v[0]);
      }
    }
  }
}

extern "C" void kernel_launch(void* const* d_in, const int* in_sizes, int n_in,
                              void* d_out, int out_size, void* d_ws, size_t ws_size,
                              hipStream_t stream) {
  (void)in_sizes; (void)n_in; (void)out_size;
  const float* noisy = (const float*)d_in[0];
  const float* memN  = (const float*)d_in[1];
  const float* memC  = (const float*)d_in[2];
  const float* bw1 = (const float*)d_in[3];
  const float* bb1 = (const float*)d_in[4];
  const float* bw2 = (const float*)d_in[5];
  const float* bb2 = (const float*)d_in[6];
  const float* bw3 = (const float*)d_in[7];
  const float* bb3 = (const float*)d_in[8];
  const float* aw1 = (const float*)d_in[9];
  const float* ab1 = (const float*)d_in[10];
  const float* aw2 = (const float*)d_in[11];
  const float* ab2 = (const float*)d_in[12];
  const float* aw3 = (const float*)d_in[13];
  const float* ab3 = (const float*)d_in[14];
  float* out_f32 = (float*)d_out;

  char* ws = (char*)d_ws;
  size_t off = 0;
  auto take = [&](size_t bytes) -> char* {
    char* p = ws + off;
    off += (bytes + 255) & ~(size_t)255;
    return p;
  };
  float* b2 = (float*)take((size_t)NMEM * 4);
  float* a2 = (float*)take((size_t)B_IMG * 4);
  ull* best = (ull*)take((size_t)B_IMG * 8);
  float* base_out = (float*)take((size_t)B_IMG * DD * 4);
  ushort* wh1b = (ushort*)take(512 * 2);
  ushort* wl1b = (ushort*)take(512 * 2);
  ushort* wh2b = (ushort*)take(2560 * 2);
  ushort* wl2b = (ushort*)take(2560 * 2);
  ushort* wh3b = (ushort*)take(2560 * 2);
  ushort* wl3b = (ushort*)take(2560 * 2);
  ushort* wh1a = (ushort*)take(512 * 2);
  ushort* wl1a = (ushort*)take(512 * 2);
  ushort* wh2a = (ushort*)take(2560 * 2);
  ushort* wl2a = (ushort*)take(2560 * 2);
  ushort* wh3a = (ushort*)take(2560 * 2);
  ushort* wl3a = (ushort*)take(2560 * 2);
  const size_t off_common = off;

  ushort* Ah = (ushort*)take((size_t)B_IMG * DD * 2);
  float* dists = (float*)take((size_t)B_IMG * NMEM * 4);
  const bool use_mfma = (off + 1024) <= ws_size;
  if (!use_mfma) off = off_common;

  // weight prep (tiny)
  wprep_kernel<<<22, 256, 0, stream>>>(bw1, bw2, bw3, 1, wh1b, wl1b, wh2b, wl2b, wh3b, wl3b);
  wprep_kernel<<<22, 256, 0, stream>>>(aw1, aw2, aw3, 3, wh1a, wl1a, wh2a, wl2a, wh3a, wl3a);

  hipMemsetAsync(best, 0xFF, (size_t)B_IMG * 8, stream);
  if (use_mfma) {
    split_hi_kernel<<<B_IMG, 256, 0, stream>>>(noisy, Ah, a2);
    dist1f_kernel<<<(NMEM / 256) * (B_IMG / 128), 512, 0, stream>>>(
        Ah, memN, a2, dists);
    refine_kernel<<<dim3(B_IMG, NCH), 256, 0, stream>>>(dists, noisy, memN, a2, best);
  } else {
    sqnorm_kernel<<<NMEM, 256, 0, stream>>>(memN, b2);
    sqnorm_kernel<<<B_IMG, 256, 0, stream>>>(noisy, a2);
    dist_argmin_kernel<<<dim3(NMEM / 128, B_IMG / 128), 256, 0, stream>>>(
        noisy, memN, a2, b2, best);
  }

  // base denoiser: base_out = noisy - conv3(relu(conv2(relu(conv1(noisy)))))
  fused_conv3_kernel<1><<<B_IMG * 25, 256, 0, stream>>>(
      noisy, nullptr, nullptr, nullptr,
      wh1b, wl1b, bb1, wh2b, wl2b, bb2, wh3b, wl3b, bb3, noisy, -1.0f, base_out);
  // adapter: out = base_out + conv3(relu(conv2(relu(conv1([noisy, base_out, memC[best]])))))
  fused_conv3_kernel<3><<<B_IMG * 25, 256, 0, stream>>>(
      noisy, base_out, memC, best,
      wh1a, wl1a, ab1, wh2a, wl2a, ab2, wh3a, wl3a, ab3, base_out, 1.0f, out_f32);
}

// Round 20
// 482.962 us; speedup vs baseline: 1.0216x; 1.0216x over previous
//
#include <hip/hip_runtime.h>
#include <hip/hip_bf16.h>
#include <cstdint>

#define B_IMG 512
#define NMEM  32768
#define DD    4096
#define HID   16

typedef __attribute__((ext_vector_type(8))) short short8;
typedef __attribute__((ext_vector_type(4))) float f32x4;
typedef unsigned long long ull;

__device__ __forceinline__ void gload16(const void* g, const void* l) {
  __builtin_amdgcn_global_load_lds(
      (const __attribute__((address_space(1))) void*)g,
      (__attribute__((address_space(3))) void*)l, 16, 0, 0);
}

__device__ __forceinline__ ushort to_bf16u(float f) {
  uint32_t u = __float_as_uint(f);
  return (ushort)((u + 0x7fffu + ((u >> 16) & 1u)) >> 16);
}

__device__ __forceinline__ uint32_t cvtpk(float lo, float hi) {
  uint32_t r;
  asm("v_cvt_pk_bf16_f32 %0, %1, %2" : "=v"(r) : "v"(lo), "v"(hi));
  return r;
}

// ---------------- squared row norms (fallback path) ----------------
__global__ __launch_bounds__(256) void sqnorm_kernel(const float* __restrict__ x,
                                                     float* __restrict__ out) {
  const int row = blockIdx.x;
  const float4* p = reinterpret_cast<const float4*>(x + (size_t)row * DD);
  float s = 0.f;
#pragma unroll
  for (int j = 0; j < 4; ++j) {
    float4 v = p[threadIdx.x + 256 * j];
    s += v.x * v.x + v.y * v.y + v.z * v.z + v.w * v.w;
  }
#pragma unroll
  for (int o = 32; o > 0; o >>= 1) s += __shfl_down(s, o);
  __shared__ float ls[4];
  if ((threadIdx.x & 63) == 0) ls[threadIdx.x >> 6] = s;
  __syncthreads();
  if (threadIdx.x == 0) out[row] = (ls[0] + ls[1]) + (ls[2] + ls[3]);
}

// ---------------- split f32 -> bf16 hi + row sqnorm (A side only) ----------------
__global__ __launch_bounds__(256) void split_hi_kernel(const float* __restrict__ x,
                                                       ushort* __restrict__ hi,
                                                       float* __restrict__ nrm) {
  const int row = blockIdx.x;
  const int t = threadIdx.x;
  const float4* p = reinterpret_cast<const float4*>(x + (size_t)row * DD);
  ushort4* ph = reinterpret_cast<ushort4*>(hi + (size_t)row * DD);
  float s = 0.f;
#pragma unroll
  for (int j = 0; j < 4; ++j) {
    float4 v = p[t + 256 * j];
    float vv[4] = {v.x, v.y, v.z, v.w};
    ushort4 h;
    ushort* hp = &h.x;
#pragma unroll
    for (int q = 0; q < 4; ++q) {
      float f = vv[q];
      s += f * f;
      hp[q] = to_bf16u(f);
    }
    ph[t + 256 * j] = h;
  }
#pragma unroll
  for (int o = 32; o > 0; o >>= 1) s += __shfl_down(s, o);
  __shared__ float ls[4];
  if ((t & 63) == 0) ls[t >> 6] = s;
  __syncthreads();
  if (t == 0) nrm[row] = (ls[0] + ls[1]) + (ls[2] + ls[3]);
}

// ---------------- pass 1: bf16 MFMA dist GEMM, B converted inline, BK=64 ------------
// r12 schedule, 8 waves/block (r17): per-wave 64x32 sub-tile.
__global__ __launch_bounds__(512) void dist1f_kernel(
    const ushort* __restrict__ Ah_g, const float* __restrict__ Bf,
    const float* __restrict__ a2, float* __restrict__ dists) {
  const int d = blockIdx.x;
  const int xcd = d & 7;
  const int rest = d >> 3;
  const int mb = rest & 3;
  const int nb = (rest >> 2) * 8 + xcd;
  const int m0 = mb * 128;
  const int n0 = nb * 128;

  __shared__ __align__(16) char la[16384];   // Ah tile 128x64 bf16 (two 128x32 halves)
  __shared__ __align__(16) char lbB[16384];  // B tile 128x64 bf16 (converted)
  __shared__ float b2loc[128];

  const int t = threadIdx.x;
  const int lane = t & 63;
  const int wid = t >> 6;        // 0..7
  const int wm = wid >> 2;       // 0..1 -> 64-row band
  const int wn = wid & 3;        // 0..3 -> 32-col band

  f32x4 acc[4][2];
#pragma unroll
  for (int mi = 0; mi < 4; ++mi)
#pragma unroll
    for (int ni = 0; ni < 2; ++ni) {
      f32x4 z = {0.f, 0.f, 0.f, 0.f};
      acc[mi][ni] = z;
    }

  const int r0 = t >> 2, g0 = t & 3;
  const int c0 = ((g0 ^ ((r0 >> 1) & 3)) << 3);
  const float* Bp0 = Bf + (size_t)(n0 + r0) * DD + c0;
  float s0 = 0.f;

  const int arow = t >> 2;
  const int acol = ((g0 ^ ((arow >> 1) & 3)) << 3);

  for (int k0 = 0; k0 < DD; k0 += 64) {
#pragma unroll
    for (int h = 0; h < 2; ++h)
      gload16(Ah_g + ((size_t)(m0 + arow) * DD + k0 + h * 32 + acol),
              la + h * 8192 + t * 16);
#pragma unroll
    for (int h = 0; h < 2; ++h) {
      float4 f00 = *(const float4*)(Bp0 + k0 + h * 32);
      float4 f01 = *(const float4*)(Bp0 + k0 + h * 32 + 4);
      s0 += f00.x * f00.x + f00.y * f00.y + f00.z * f00.z + f00.w * f00.w;
      s0 += f01.x * f01.x + f01.y * f01.y + f01.z * f01.z + f01.w * f01.w;
      uint4 p0;
      p0.x = cvtpk(f00.x, f00.y); p0.y = cvtpk(f00.z, f00.w);
      p0.z = cvtpk(f01.x, f01.y); p0.w = cvtpk(f01.z, f01.w);
      *(uint4*)(lbB + h * 8192 + t * 16) = p0;
    }
    __syncthreads();

#pragma unroll
    for (int h = 0; h < 2; ++h) {
      short8 ah[4];
#pragma unroll
      for (int mi = 0; mi < 4; ++mi) {
        const int r = wm * 64 + mi * 16 + (lane & 15);
        const int off = r * 64 + ((((lane >> 4) ^ (r >> 1)) & 3) << 4);
        ah[mi] = *(const short8*)(la + h * 8192 + off);
      }
#pragma unroll
      for (int ni = 0; ni < 2; ++ni) {
        const int r = wn * 32 + ni * 16 + (lane & 15);
        const int off = r * 64 + ((((lane >> 4) ^ (r >> 1)) & 3) << 4);
        short8 bh = *(const short8*)(lbB + h * 8192 + off);
#pragma unroll
        for (int mi = 0; mi < 4; ++mi)
          acc[mi][ni] = __builtin_amdgcn_mfma_f32_16x16x32_bf16(ah[mi], bh, acc[mi][ni], 0, 0, 0);
      }
    }
    __syncthreads();
  }

  s0 += __shfl_xor(s0, 1); s0 += __shfl_xor(s0, 2);
  if ((t & 3) == 0) b2loc[r0] = s0;
  __syncthreads();

#pragma unroll
  for (int mi = 0; mi < 4; ++mi)
#pragma unroll
    for (int j = 0; j < 4; ++j) {
      const int m = m0 + wm * 64 + mi * 16 + (lane >> 4) * 4 + j;
      const float a2v = a2[m];
#pragma unroll
      for (int ni = 0; ni < 2; ++ni) {
        const int nl = wn * 32 + ni * 16 + (lane & 15);
        dists[(size_t)m * NMEM + n0 + nl] = (a2v + b2loc[nl]) - 2.0f * acc[mi][ni][j];
      }
    }
}

// ---------------- pass 2: chunked approx-min -> candidates -> exact refine ----------------
#define MARGIN 4.0f
#define MAXC 64
#define NCH 4
#define CHW (NMEM / NCH)
__global__ __launch_bounds__(256) void refine_kernel(
    const float* __restrict__ dists, const float* __restrict__ A,
    const float* __restrict__ Bm, const float* __restrict__ a2,
    ull* __restrict__ best) {
  const int m = blockIdx.x;
  const int base = blockIdx.y * CHW;
  const int t = threadIdx.x;
  const int lane = t & 63, wid = t >> 6;
  const float4* r4 = reinterpret_cast<const float4*>(dists + (size_t)m * NMEM + base);

  float lmin = 3.4e38f;
  for (int i = t; i < CHW / 4; i += 256) {
    float4 v = r4[i];
    lmin = fminf(lmin, fminf(fminf(v.x, v.y), fminf(v.z, v.w)));
  }
#pragma unroll
  for (int o = 32; o > 0; o >>= 1) lmin = fminf(lmin, __shfl_down(lmin, o));
  __shared__ float ws4[4];
  __shared__ float red[4];
  __shared__ float red2[4];
  __shared__ int cnt;
  __shared__ int cand[MAXC];
  if (lane == 0) ws4[wid] = lmin;
  if (t == 0) cnt = 0;
  __syncthreads();
  const float thresh = fminf(fminf(ws4[0], ws4[1]), fminf(ws4[2], ws4[3])) + MARGIN;

  for (int i = t; i < CHW / 4; i += 256) {
    float4 v = r4[i];
    float vv[4] = {v.x, v.y, v.z, v.w};
#pragma unroll
    for (int q = 0; q < 4; ++q)
      if (vv[q] < thresh) {
        int c = atomicAdd(&cnt, 1);
        if (c < MAXC) cand[c] = base + i * 4 + q;
      }
  }
  __syncthreads();
  const int nc = min(cnt, MAXC);

  ull bkey = ~0ull;
  const float4* a4 = reinterpret_cast<const float4*>(A + (size_t)m * DD);
  for (int c = 0; c < nc; ++c) {
    const int n = cand[c];
    const float4* b4 = reinterpret_cast<const float4*>(Bm + (size_t)n * DD);
    float s = 0.f, s2 = 0.f;
    for (int i = t; i < DD / 4; i += 256) {
      float4 av = a4[i], bv = b4[i];
      s += av.x * bv.x + av.y * bv.y + av.z * bv.z + av.w * bv.w;
      s2 += bv.x * bv.x + bv.y * bv.y + bv.z * bv.z + bv.w * bv.w;
    }
#pragma unroll
    for (int o = 32; o > 0; o >>= 1) {
      s += __shfl_down(s, o);
      s2 += __shfl_down(s2, o);
    }
    if (lane == 0) { red[wid] = s; red2[wid] = s2; }
    __syncthreads();
    if (t == 0) {
      const float dot = (red[0] + red[1]) + (red[2] + red[3]);
      const float b2n = (red2[0] + red2[1]) + (red2[2] + red2[3]);
      const float dv = (a2[m] + b2n) - 2.0f * dot;
      const ull key = ((ull)__float_as_uint(dv) << 32) | (unsigned)n;
      if (key < bkey) bkey = key;
    }
    __syncthreads();
  }
  if (t == 0) atomicMin(&best[m], bkey);
}

// ---------------- fp32 fallback distance GEMM + argmin ----------------
__global__ __launch_bounds__(256) void dist_argmin_kernel(
    const float* __restrict__ A, const float* __restrict__ Bm,
    const float* __restrict__ a2, const float* __restrict__ b2,
    ull* __restrict__ best) {
  __shared__ float As[32][128];
  __shared__ float Bs[32][128];
  const int tid = threadIdx.x;
  const int m0 = blockIdx.y * 128;
  const int n0 = blockIdx.x * 128;
  const int tm = tid >> 4, tn = tid & 15;
  const int sr = tid >> 3;
  const int sc = (tid & 7) << 2;
  float acc[8][8];
#pragma unroll
  for (int i = 0; i < 8; ++i)
#pragma unroll
    for (int j = 0; j < 8; ++j) acc[i][j] = 0.f;
  for (int k0 = 0; k0 < DD; k0 += 32) {
    __syncthreads();
#pragma unroll
    for (int r = 0; r < 4; ++r) {
      const int row = sr + (r << 5);
      float4 va = *reinterpret_cast<const float4*>(&A[(size_t)(m0 + row) * DD + k0 + sc]);
      As[sc + 0][row] = va.x; As[sc + 1][row] = va.y;
      As[sc + 2][row] = va.z; As[sc + 3][row] = va.w;
      float4 vb = *reinterpret_cast<const float4*>(&Bm[(size_t)(n0 + row) * DD + k0 + sc]);
      Bs[sc + 0][row] = vb.x; Bs[sc + 1][row] = vb.y;
      Bs[sc + 2][row] = vb.z; Bs[sc + 3][row] = vb.w;
    }
    __syncthreads();
#pragma unroll 8
    for (int kk = 0; kk < 32; ++kk) {
      float4 a0 = *reinterpret_cast<const float4*>(&As[kk][tm * 8]);
      float4 a1 = *reinterpret_cast<const float4*>(&As[kk][tm * 8 + 4]);
      float4 b0 = *reinterpret_cast<const float4*>(&Bs[kk][tn * 8]);
      float4 b1 = *reinterpret_cast<const float4*>(&Bs[kk][tn * 8 + 4]);
      float a[8] = {a0.x, a0.y, a0.z, a0.w, a1.x, a1.y, a1.z, a1.w};
      float b[8] = {b0.x, b0.y, b0.z, b0.w, b1.x, b1.y, b1.z, b1.w};
#pragma unroll
      for (int i = 0; i < 8; ++i)
#pragma unroll
        for (int j = 0; j < 8; ++j) acc[i][j] += a[i] * b[j];
    }
  }
  __syncthreads();
  ull* red = reinterpret_cast<ull*>(&As[0][0]);
#pragma unroll
  for (int i = 0; i < 8; ++i) {
    const int m = m0 + tm * 8 + i;
    const float a2v = a2[m];
    float bd = 3.4e38f;
    int bn = 0;
#pragma unroll
    for (int j = 0; j < 8; ++j) {
      const int n = n0 + tn * 8 + j;
      const float dval = (a2v + b2[n]) - 2.0f * acc[i][j];
      if (dval < bd) { bd = dval; bn = n; }
    }
    red[(tm * 8 + i) * 16 + tn] = ((ull)__float_as_uint(bd) << 32) | (unsigned)bn;
  }
  __syncthreads();
  if (tid < 128) {
    ull k = red[tid * 16];
#pragma unroll
    for (int t2 = 1; t2 < 16; ++t2) {
      ull c = red[tid * 16 + t2];
      if (c < k) k = c;
    }
    atomicMin(&best[m0 + tid], k);
  }
}

// ---------------- weight prep per pipeline ----------------
// wh1/wl1: [co][32k] bf16 hi/lo, k = ci*9+tap (k >= ncin*9 -> 0)  (L1 MFMA A-operand)
// wh2/wl2: [co][160] bf16 hi/lo, k = tap*16+ci
// wh3/wl3: [16][160] bf16 hi/lo, row 0 = w3
__global__ __launch_bounds__(256) void wprep_kernel(
    const float* __restrict__ w1, const float* __restrict__ w2,
    const float* __restrict__ w3, int ncin,
    ushort* __restrict__ wh1, ushort* __restrict__ wl1,
    ushort* __restrict__ wh2, ushort* __restrict__ wl2,
    ushort* __restrict__ wh3, ushort* __restrict__ wl3) {
  const int i = blockIdx.x * 256 + threadIdx.x;
  if (i < 512) {
    const int co = i >> 5, k = i & 31;
    float f = 0.f;
    if (k < ncin * 9) f = w1[(co * ncin + k / 9) * 9 + (k % 9)];
    const ushort hb = to_bf16u(f);
    const float fl = f - __uint_as_float((uint32_t)hb << 16);
    wh1[i] = hb;
    wl1[i] = to_bf16u(fl);
  } else if (i < 512 + 5120) {
    const int j = i - 512;
    const int which = j / 2560;        // 0 -> L2, 1 -> L3
    const int jj = j % 2560;
    const int co = jj / 160, k = jj % 160;
    float f = 0.f;
    if (which == 0) {
      if (k < 144) f = w2[co * 144 + (k & 15) * 9 + (k >> 4)];
    } else {
      if (co == 0 && k < 144) f = w3[(k & 15) * 9 + (k >> 4)];
    }
    const ushort hb = to_bf16u(f);
    const float fl = f - __uint_as_float((uint32_t)hb << 16);
    ushort* dh = (which == 0) ? wh2 : wh3;
    ushort* dl = (which == 0) ? wl2 : wl3;
    dh[co * 160 + k] = hb;
    dl[co * 160 + k] = to_bf16u(fl);
  }
}

// ---------------- fused 3-layer conv: ALL layers MFMA ----------------
template <int NCIN>
__global__ __launch_bounds__(256, 4) void fused_conv3_kernel(
    const float* __restrict__ chan0, const float* __restrict__ chan1,
    const float* __restrict__ memC, const ull* __restrict__ best,
    const ushort* __restrict__ wh1, const ushort* __restrict__ wl1,
    const float* __restrict__ b1v,
    const ushort* __restrict__ wh2, const ushort* __restrict__ wl2,
    const float* __restrict__ b2v,
    const ushort* __restrict__ wh3, const ushort* __restrict__ wl3,
    const float* __restrict__ b3v,
    const float* __restrict__ addend, float sign, float* __restrict__ outp) {
  constexpr int SIN_SZ = NCIN * 1600;      // [ci][20][20] f32
  constexpr int H1 = SIN_SZ;               // 2 planes x 5184 B
  constexpr int H2 = H1 + 10368;           // 2 planes x 5184 B
  constexpr int ZP = H2 + 10368;           // 64 B zeros
  constexpr int SB = ZP + 64;              // 16 f32 b1 | 16 f32 b2
  __shared__ __align__(16) char smem[SB + 128];
  float* sIn = (float*)smem;
  float* sB = (float*)(smem + SB);

  const int tid = threadIdx.x;
  const int lane = tid & 63, wid = tid >> 6;
  const int img = blockIdx.x / 25;
  const int t = blockIdx.x % 25;
  const int y0 = (t / 5) * 14, x0 = (t % 5) * 14;

  const float* cptr[NCIN];
  cptr[0] = chan0 + (size_t)img * DD;
  if (NCIN == 3) {
    cptr[1] = chan1 + (size_t)img * DD;
    cptr[2] = memC + (size_t)(unsigned)(best[img] & 0xffffffffull) * DD;
  }

  if (tid < 16) *(float*)(smem + ZP + tid * 4) = 0.f;
  if (tid < 16) sB[tid] = b1v[tid];
  else if (tid < 32) sB[tid] = b2v[tid - 16];
  // stage input 20x20 per channel (global offset -3)
  for (int i = tid; i < NCIN * 400; i += 256) {
    const int ci = i / 400, r = i % 400, yy = r / 20, xx = r % 20;
    const int gy = y0 + yy - 3, gx = x0 + xx - 3;
    float v = 0.f;
    if (gy >= 0 && gy < 64 && gx >= 0 && gx < 64) v = cptr[ci][gy * 64 + gx];
    sIn[ci * 400 + yy * 20 + xx] = v;
  }
  __syncthreads();

  // ---- L1 (MFMA): D[co][px] over 18x18 px, K = ci*9+tap padded to 32 ----
  {
    const int xn15 = lane & 15;
    const int kb = (lane >> 4) * 8;
    const short8 a_hi = *(const short8*)(wh1 + xn15 * 32 + kb);
    const short8 a_lo = *(const short8*)(wl1 + xn15 * 32 + kb);
    int koff[8];
    bool kval[8];
#pragma unroll
    for (int e = 0; e < 8; ++e) {
      const int k = kb + e;
      kval[e] = (k < NCIN * 9);
      const int ci = k / 9, kk = k % 9;
      koff[e] = ci * 400 + (kk / 3) * 20 + (kk % 3);
    }
    for (int g = wid; g < 21; g += 4) {
      const int pxl = g * 16 + xn15;
      const bool pv = (pxl < 324);
      const int py = pxl / 18, pxx = pxl % 18;
      const int pbase = py * 20 + pxx;
      float v[8];
#pragma unroll
      for (int e = 0; e < 8; ++e)
        v[e] = (kval[e] && pv) ? sIn[pbase + koff[e]] : 0.f;
      uint4 bu;
      bu.x = cvtpk(v[0], v[1]); bu.y = cvtpk(v[2], v[3]);
      bu.z = cvtpk(v[4], v[5]); bu.w = cvtpk(v[6], v[7]);
      short8 b = *reinterpret_cast<short8*>(&bu);
      f32x4 z = {0.f, 0.f, 0.f, 0.f};
      f32x4 a1 = __builtin_amdgcn_mfma_f32_16x16x32_bf16(a_lo, b, z, 0, 0, 0);
      a1 = __builtin_amdgcn_mfma_f32_16x16x32_bf16(a_hi, b, a1, 0, 0, 0);
      const int gy = y0 + py - 2, gx = x0 + pxx - 2;
      const bool inimg = pv && ((unsigned)gy < 64u) && ((unsigned)gx < 64u);
      if (pv) {
#pragma unroll
        for (int j = 0; j < 4; ++j) {
          const int co = (lane >> 4) * 4 + j;
          const float val = inimg ? fmaxf(a1[j] + sB[co], 0.f) : 0.f;
          *(ushort*)(smem + H1 + (co >> 3) * 5184 + pxl * 16 + (co & 7) * 2) =
              to_bf16u(val);
        }
      }
    }
  }
  __syncthreads();

  // ---- L2 (MFMA) -> h2 bf16 planes on 16x16 grid; zero outside image ----
  const int xn = lane & 15;
  const int xk = lane >> 4;
  f32x4 acc2[4];
#pragma unroll
  for (int g = 0; g < 4; ++g) { f32x4 z = {0.f, 0.f, 0.f, 0.f}; acc2[g] = z; }
#pragma unroll
  for (int kq = 0; kq < 5; ++kq) {
    const int k0 = kq * 32;
    const int we = xn * 160 + k0 + xk * 8;
    short8 ah = *(const short8*)(wh2 + we);
    short8 al = *(const short8*)(wl2 + we);
    const int kb = k0 + xk * 8;
    const int tap = kb >> 4, cih = (kb >> 3) & 1;
    const bool zp = (tap >= 9);
    const int dy = tap / 3, dx = tap % 3;
    const int bbase = H1 + cih * 5184 + ((dy * 18) + xn + dx) * 16;
#pragma unroll
    for (int g = 0; g < 4; ++g) {
      const int y = wid * 4 + g;
      const int boff = zp ? ZP : (bbase + y * 288);
      short8 b = *(const short8*)(smem + boff);
      acc2[g] = __builtin_amdgcn_mfma_f32_16x16x32_bf16(ah, b, acc2[g], 0, 0, 0);
      acc2[g] = __builtin_amdgcn_mfma_f32_16x16x32_bf16(al, b, acc2[g], 0, 0, 0);
    }
  }
#pragma unroll
  for (int g = 0; g < 4; ++g) {
    const int y = wid * 4 + g;
    const int gy = y0 + y - 1, gx = x0 + xn - 1;
    const bool inimg = ((unsigned)gy < 64u) && ((unsigned)gx < 64u);
#pragma unroll
    for (int j = 0; j < 4; ++j) {
      const int co = xk * 4 + j;
      const float v = inimg ? fmaxf(acc2[g][j] + sB[16 + co], 0.f) : 0.f;
      *(ushort*)(smem + H2 + (co >> 3) * 5184 + (y * 18 + xn) * 16 + (co & 7) * 2) =
          to_bf16u(v);
    }
  }
  __syncthreads();

  // ---- L3 (MFMA, only D-row co=0 used) + epilogue on 14x14 ----
  f32x4 acc3[4];
#pragma unroll
  for (int g = 0; g < 4; ++g) { f32x4 z = {0.f, 0.f, 0.f, 0.f}; acc3[g] = z; }
#pragma unroll
  for (int kq = 0; kq < 5; ++kq) {
    const int k0 = kq * 32;
    const int we = xn * 160 + k0 + xk * 8;
    short8 ah = *(const short8*)(wh3 + we);
    short8 al = *(const short8*)(wl3 + we);
    const int kb = k0 + xk * 8;
    const int tap = kb >> 4, cih = (kb >> 3) & 1;
    const bool zp = (tap >= 9);
    const int dy = tap / 3, dx = tap % 3;
    const int bbase = H2 + cih * 5184 + ((dy * 18) + xn + dx) * 16;
#pragma unroll
    for (int g = 0; g < 4; ++g) {
      const int y = wid * 4 + g;
      const int boff = zp ? ZP : (bbase + y * 288);
      short8 b = *(const short8*)(smem + boff);
      acc3[g] = __builtin_amdgcn_mfma_f32_16x16x32_bf16(ah, b, acc3[g], 0, 0, 0);
      acc3[g] = __builtin_amdgcn_mfma_f32_16x16x32_bf16(al, b, acc3[g], 0, 0, 0);
    }
  }
  if (xk == 0) {
#pragma unroll
    for (int g = 0; g < 4; ++g) {
      const int y = wid * 4 + g;
      const int gy = y0 + y, gx = x0 + xn;
      if (y < 14 && xn < 14 && gy < 64 && gx < 64) {
        const size_t o = (size_t)img * DD + gy * 64 + gx;
        outp[o] = addend[o] + sign * (acc3[g][0] + b3v[0]);
      }
    }
  }
}

extern "C" void kernel_launch(void* const* d_in, const int* in_sizes, int n_in,
                              void* d_out, int out_size, void* d_ws, size_t ws_size,
                              hipStream_t stream) {
  (void)in_sizes; (void)n_in; (void)out_size;
  const float* noisy = (const float*)d_in[0];
  const float* memN  = (const float*)d_in[1];
  const float* memC  = (const float*)d_in[2];
  const float* bw1 = (const float*)d_in[3];
  const float* bb1 = (const float*)d_in[4];
  const float* bw2 = (const float*)d_in[5];
  const float* bb2 = (const float*)d_in[6];
  const float* bw3 = (const float*)d_in[7];
  const float* bb3 = (const float*)d_in[8];
  const float* aw1 = (const float*)d_in[9];
  const float* ab1 = (const float*)d_in[10];
  const float* aw2 = (const float*)d_in[11];
  const float* ab2 = (const float*)d_in[12];
  const float* aw3 = (const float*)d_in[13];
  const float* ab3 = (const float*)d_in[14];
  float* out_f32 = (float*)d_out;

  char* ws = (char*)d_ws;
  size_t off = 0;
  auto take = [&](size_t bytes) -> char* {
    char* p = ws + off;
    off += (bytes + 255) & ~(size_t)255;
    return p;
  };
  float* b2 = (float*)take((size_t)NMEM * 4);
  float* a2 = (float*)take((size_t)B_IMG * 4);
  ull* best = (ull*)take((size_t)B_IMG * 8);
  float* base_out = (float*)take((size_t)B_IMG * DD * 4);
  ushort* wh1b = (ushort*)take(512 * 2);
  ushort* wl1b = (ushort*)take(512 * 2);
  ushort* wh2b = (ushort*)take(2560 * 2);
  ushort* wl2b = (ushort*)take(2560 * 2);
  ushort* wh3b = (ushort*)take(2560 * 2);
  ushort* wl3b = (ushort*)take(2560 * 2);
  ushort* wh1a = (ushort*)take(512 * 2);
  ushort* wl1a = (ushort*)take(512 * 2);
  ushort* wh2a = (ushort*)take(2560 * 2);
  ushort* wl2a = (ushort*)take(2560 * 2);
  ushort* wh3a = (ushort*)take(2560 * 2);
  ushort* wl3a = (ushort*)take(2560 * 2);
  const size_t off_common = off;

  ushort* Ah = (ushort*)take((size_t)B_IMG * DD * 2);
  float* dists = (float*)take((size_t)B_IMG * NMEM * 4);
  const bool use_mfma = (off + 1024) <= ws_size;
  if (!use_mfma) off = off_common;

  // weight prep (tiny)
  wprep_kernel<<<22, 256, 0, stream>>>(bw1, bw2, bw3, 1, wh1b, wl1b, wh2b, wl2b, wh3b, wl3b);
  wprep_kernel<<<22, 256, 0, stream>>>(aw1, aw2, aw3, 3, wh1a, wl1a, wh2a, wl2a, wh3a, wl3a);

  hipMemsetAsync(best, 0xFF, (size_t)B_IMG * 8, stream);
  if (use_mfma) {
    split_hi_kernel<<<B_IMG, 256, 0, stream>>>(noisy, Ah, a2);
    dist1f_kernel<<<(NMEM / 128) * (B_IMG / 128), 512, 0, stream>>>(
        Ah, memN, a2, dists);
    refine_kernel<<<dim3(B_IMG, NCH), 256, 0, stream>>>(dists, noisy, memN, a2, best);
  } else {
    sqnorm_kernel<<<NMEM, 256, 0, stream>>>(memN, b2);
    sqnorm_kernel<<<B_IMG, 256, 0, stream>>>(noisy, a2);
    dist_argmin_kernel<<<dim3(NMEM / 128, B_IMG / 128), 256, 0, stream>>>(
        noisy, memN, a2, b2, best);
  }

  // base denoiser: base_out = noisy - conv3(relu(conv2(relu(conv1(noisy)))))
  fused_conv3_kernel<1><<<B_IMG * 25, 256, 0, stream>>>(
      noisy, nullptr, nullptr, nullptr,
      wh1b, wl1b, bb1, wh2b, wl2b, bb2, wh3b, wl3b, bb3, noisy, -1.0f, base_out);
  // adapter: out = base_out + conv3(relu(conv2(relu(conv1([noisy, base_out, memC[best]])))))
  fused_conv3_kernel<3><<<B_IMG * 25, 256, 0, stream>>>(
      noisy, base_out, memC, best,
      wh1a, wl1a, ab1, wh2a, wl2a, ab2, wh3a, wl3a, ab3, base_out, 1.0f, out_f32);
}